// Round 9
// baseline (918.313 us; speedup 1.0000x reference)
//
#include <hip/hip_runtime.h>
#include <hip/hip_bf16.h>
#include <hip/hip_fp16.h>
#include <cstdint>

typedef __attribute__((ext_vector_type(8))) short short8;   // 8 bf16 = 4 VGPRs
typedef __attribute__((ext_vector_type(4))) float floatx4;  // 4 fp32 acc
typedef __attribute__((ext_vector_type(4))) int   intx4;    // for nontemporal ld

#define LEAKY_ALPHA 0.2f

__device__ __forceinline__ unsigned short f2bf_rne(float f) {
    unsigned u = __float_as_uint(f);
    unsigned r = u + 0x7FFFu + ((u >> 16) & 1u);   // round-to-nearest-even
    return (unsigned short)(r >> 16);
}

__device__ __forceinline__ unsigned pk2bf(float lo, float hi) {   // v_cvt_pk_bf16_f32
    union { __hip_bfloat162 b; unsigned u; } c;
    c.b = __float22bfloat162_rn(make_float2(lo, hi));
    return c.u;
}

__device__ __forceinline__ float2 h2f2(unsigned w) {
    union { unsigned u; __half2 h; } c; c.u = w;
    return __half22float2(c.h);
}

// ---------------------------------------------------------------------------
// Kernel 0: pack adj (512 MiB int32) -> bitmask (16 MiB), sequential stream,
// NON-TEMPORAL loads so the stream never pollutes L2/L3 for later kernels.
// Thread t: 32 consecutive ints -> 1 dword (bit j = col t*32+j > 0).
// ---------------------------------------------------------------------------
__global__ __launch_bounds__(256) void k_pack(const int* __restrict__ adj,
                                              unsigned* __restrict__ mask) {
    const size_t t = (size_t)blockIdx.x * 256 + threadIdx.x;
    const int* p = adj + t * 32;
    unsigned m = 0;
    #pragma unroll
    for (int k = 0; k < 8; ++k) {
        const intx4 v = __builtin_nontemporal_load((const intx4*)(p + k * 4));
        m |= (v.x > 0 ? 1u : 0u) << (k * 4 + 0);
        m |= (v.y > 0 ? 1u : 0u) << (k * 4 + 1);
        m |= (v.z > 0 ? 1u : 0u) << (k * 4 + 2);
        m |= (v.w > 0 ? 1u : 0u) << (k * 4 + 3);
    }
    mask[t] = m;
}

// ---------------------------------------------------------------------------
// Kernel 1: h = inp @ W (fp32); e1=(exp(s1),exp(.2*s1)) fp32 per row,
// e2h=(exp(s2),exp(.2*s2)) half2 per col; hT bf16 TILED (plain order):
// [b][tile=n/32][o(64)][nc=n%32] — 4 KB contiguous per 32-col K-window.
// ---------------------------------------------------------------------------
__global__ __launch_bounds__(256) void k_h(const float* __restrict__ inp,
                                           const float* __restrict__ W,
                                           const float* __restrict__ a,
                                           unsigned short* __restrict__ hT,
                                           float2* __restrict__ e1,
                                           __half2* __restrict__ e2h) {
    __shared__ float hs[64][65];   // +1 pad
    const int tid  = threadIdx.x;
    const int wv   = tid >> 6;
    const int lane = tid & 63;
    const int blk  = blockIdx.x;
    const int b     = blk >> 6;         // 0..7
    const int ibase = (blk & 63) * 64;  // row tile base

    const float a1 = a[lane];
    const float a2 = a[64 + lane];

    for (int rr = 0; rr < 16; ++rr) {
        const int rloc = wv * 16 + rr;
        const int row  = ibase + rloc;
        const float* ip = inp + ((size_t)(b * 4096 + row)) * 128;  // wave-uniform
        float acc = 0.f;
        #pragma unroll
        for (int f = 0; f < 128; f += 4) {
            float4 v = *(const float4*)(ip + f);   // uniform -> s_load
            acc += v.x * W[(f + 0) * 64 + lane];
            acc += v.y * W[(f + 1) * 64 + lane];
            acc += v.z * W[(f + 2) * 64 + lane];
            acc += v.w * W[(f + 3) * 64 + lane];
        }
        hs[rloc][lane] = acc;
        float r1 = acc * a1;
        float r2 = acc * a2;
        #pragma unroll
        for (int off = 32; off > 0; off >>= 1) {
            r1 += __shfl_xor(r1, off);
            r2 += __shfl_xor(r2, off);
        }
        if (lane == 0) {
            e1[b * 4096 + row]  = make_float2(__expf(r1), __expf(LEAKY_ALPHA * r1));
            e2h[b * 4096 + row] = __floats2half2_rn(__expf(r2), __expf(LEAKY_ALPHA * r2));
        }
    }
    __syncthreads();

    // write tiled hT[b][tile][o][nc]: thread (o, half) writes 16 consecutive nc
    const int o    = tid & 63;
    const int half = tid >> 6;          // 0..3
    const int tl   = half >> 1;         // local tile 0..1
    const int nco  = (half & 1) * 16;   // nc offset 0 or 16
    unsigned pk[8];
    #pragma unroll
    for (int s = 0; s < 16; s += 2) {
        unsigned lo = f2bf_rne(hs[tl * 32 + nco + s    ][o]);   // row uniform/wave
        unsigned hi = f2bf_rne(hs[tl * 32 + nco + s + 1][o]);
        pk[s >> 1] = lo | (hi << 16);
    }
    const int tile = (ibase >> 5) + tl;
    unsigned short* dst = hT + (((size_t)b * 128 + tile) * 64 + o) * 32 + nco;
    *(int4*)(dst)     = *(int4*)&pk[0];
    *(int4*)(dst + 8) = *(int4*)&pk[4];
}

// ---------------------------------------------------------------------------
// Kernel 2: masked softmax + PV via MFMA. Reads NO adj: its 16 KB mask slice
// is staged global->LDS once (no per-step global mask latency). hT streams
// from L2 (4 MiB, resident — no adj stream in this kernel to evict it).
// Factorized exp: p = E1p*E2p>1 ? E1p*E2p : E1n*E2n  (no exp in hot loop).
// grid 1024 (8 b x 128 row-tiles of 32), block 256 = 4 waves, 4 blocks/CU.
// ---------------------------------------------------------------------------
__global__ __launch_bounds__(256, 4) void k_attn(const unsigned* __restrict__ mask,
                                                 const unsigned short* __restrict__ hT,
                                                 const float2* __restrict__ e1g,
                                                 const __half2* __restrict__ e2hg,
                                                 float* __restrict__ out) {
    __shared__ unsigned maskl[32][132];   // [local row][col/32], stride 132 (16B-aligned rows), 16.9 KB
    __shared__ unsigned e2su[4096];       // per-col (E2p,E2n) half2 bits, 16 KB

    const int tid   = threadIdx.x;
    const int b     = blockIdx.x >> 7;
    const int rtile = blockIdx.x & 127;
    const int wv    = tid >> 6;
    const int lane  = tid & 63;

    {   // stage e2h for this batch (16 KB)
        const unsigned* src = (const unsigned*)(e2hg + b * 4096);
        #pragma unroll
        for (int t = 0; t < 4; ++t) {
            int idx = tid * 16 + t * 4;
            *(int4*)&e2su[idx] = *(const int4*)(src + idx);
        }
    }
    {   // stage this block's mask slice (32 rows x 128 words = 16 KB), NT
        const unsigned* gm = mask + ((size_t)(b * 4096 + rtile * 32)) * 128;
        #pragma unroll
        for (int q = 0; q < 4; ++q) {
            const int f = tid * 16 + q * 4;
            const intx4 v = __builtin_nontemporal_load((const intx4*)(gm + f));
            *(intx4*)&maskl[f >> 7][f & 127] = v;
        }
    }
    __syncthreads();

    // ---- Phase B: factorized masked softmax + PV via MFMA ----
    const int jhalf = wv >> 1;
    const int m     = lane & 15;
    const int kh    = lane >> 4;          // 0..3
    const int rl    = (wv & 1) * 16 + m;  // local row 0..31
    const int rbase = rtile * 32 + (wv & 1) * 16;
    const int row   = rbase + m;

    const float2 E1 = e1g[b * 4096 + row];
    const float E1p = E1.x, E1n = E1.y;
    const int jb0 = jhalf * 2048 + kh * 8;           // e2su col base
    const unsigned* mrow = &maskl[rl][jhalf * 64];   // LDS mask words

    const unsigned short* hbase =
        hT + (((size_t)b * 128 + jhalf * 64) * 64 + m) * 32 + kh * 8;
    const unsigned short* hrow0 = hbase;
    const unsigned short* hrow1 = hbase + 512;    // +16 o
    const unsigned short* hrow2 = hbase + 1024;   // +32 o
    const unsigned short* hrow3 = hbase + 1536;   // +48 o

    floatx4 acc0 = (floatx4){0.f,0.f,0.f,0.f};
    floatx4 acc1 = (floatx4){0.f,0.f,0.f,0.f};
    floatx4 acc2 = (floatx4){0.f,0.f,0.f,0.f};
    floatx4 acc3 = (floatx4){0.f,0.f,0.f,0.f};
    float lsum = 0.f;

    // depth-2 ring: named scalars, slot is a compile-time macro token
    unsigned rm_0, rm_1;
    short8 rb0_0, rb1_0, rb2_0, rb3_0, rb0_1, rb1_1, rb2_1, rb3_1;

    rm_0  = mrow[0];
    rb0_0 = *(const short8*)(hrow0);         rb1_0 = *(const short8*)(hrow1);
    rb2_0 = *(const short8*)(hrow2);         rb3_0 = *(const short8*)(hrow3);
    rm_1  = mrow[1];
    rb0_1 = *(const short8*)(hrow0 + 2048);  rb1_1 = *(const short8*)(hrow1 + 2048);
    rb2_1 = *(const short8*)(hrow2 + 2048);  rb3_1 = *(const short8*)(hrow3 + 2048);

#define GAT_COL(WRD, T)                                                        \
    {                                                                          \
        const float2 ef = h2f2((unsigned)(WRD));                               \
        const float P  = E1p * ef.x;                                           \
        const float Nn = E1n * ef.y;                                           \
        float p = (P > 1.0f) ? P : Nn;                                         \
        p = ((mb >> (T)) & 1u) ? p : 0.0f;                                     \
        psum += p;                                                             \
        pv[T] = p;                                                             \
    }

#define GAT_STEP(SL, STEPIDX)                                                  \
    do {                                                                       \
        const unsigned cmw = rm_##SL;                                          \
        const short8 cb0 = rb0_##SL, cb1 = rb1_##SL;                           \
        const short8 cb2 = rb2_##SL, cb3 = rb3_##SL;                           \
        const int pstep = ((STEPIDX) + 2) & 63;        /* wrap: no OOB tail */ \
        const int poff = pstep * 2048;                 /* 4 KB tiles */        \
        rm_##SL  = mrow[pstep];                                                \
        rb0_##SL = *(const short8*)(hrow0 + poff);                             \
        rb1_##SL = *(const short8*)(hrow1 + poff);                             \
        rb2_##SL = *(const short8*)(hrow2 + poff);                             \
        rb3_##SL = *(const short8*)(hrow3 + poff);                             \
        const int soff = jb0 + (STEPIDX) * 32;                                 \
        const int4 eA = *(const int4*)&e2su[soff];                             \
        const int4 eB = *(const int4*)&e2su[soff + 4];                         \
        const unsigned mb = (cmw >> (kh * 8)) & 0xffu;                         \
        float pv[8];                                                           \
        float psum = 0.f;                                                      \
        GAT_COL(eA.x, 0) GAT_COL(eA.y, 1) GAT_COL(eA.z, 2) GAT_COL(eA.w, 3)    \
        GAT_COL(eB.x, 4) GAT_COL(eB.y, 5) GAT_COL(eB.z, 6) GAT_COL(eB.w, 7)    \
        lsum += psum;                                                          \
        int4 ai;                                                               \
        ai.x = pk2bf(pv[0], pv[1]); ai.y = pk2bf(pv[2], pv[3]);                \
        ai.z = pk2bf(pv[4], pv[5]); ai.w = pk2bf(pv[6], pv[7]);                \
        union { int4 i; short8 s; } cc; cc.i = ai;                             \
        const short8 af = cc.s;                                                \
        acc0 = __builtin_amdgcn_mfma_f32_16x16x32_bf16(af, cb0, acc0, 0,0,0);  \
        acc1 = __builtin_amdgcn_mfma_f32_16x16x32_bf16(af, cb1, acc1, 0,0,0);  \
        acc2 = __builtin_amdgcn_mfma_f32_16x16x32_bf16(af, cb2, acc2, 0,0,0);  \
        acc3 = __builtin_amdgcn_mfma_f32_16x16x32_bf16(af, cb3, acc3, 0,0,0);  \
    } while (0)

    #pragma unroll 1
    for (int it = 0; it < 32; ++it) {
        const int s0 = it * 2;
        GAT_STEP(0, s0);
        GAT_STEP(1, s0 + 1);
    }
#undef GAT_STEP
#undef GAT_COL

    // reduce rowsum across the 4 kh-groups
    lsum += __shfl_xor(lsum, 16);
    lsum += __shfl_xor(lsum, 32);

    floatx4 accs[4] = {acc0, acc1, acc2, acc3};

    // epilogue scratch aliases the (now dead) mask LDS: [2][64][17] + [2][64]
    float* accb = (float*)&maskl[0][0];
    float* lb   = accb + 2 * 64 * 17;

    __syncthreads();   // mask no longer needed by any wave
    if (wv >= 2) {
        #pragma unroll
        for (int f = 0; f < 4; ++f)
            #pragma unroll
            for (int r = 0; r < 4; ++r)
                accb[(wv - 2) * 64 * 17 + lane * 17 + f * 4 + r] = accs[f][r];
        lb[(wv - 2) * 64 + lane] = lsum;
    }
    __syncthreads();
    if (wv < 2) {
        const float ltot = lsum + lb[wv * 64 + lane];
        #pragma unroll
        for (int f = 0; f < 4; ++f) {
            #pragma unroll
            for (int r = 0; r < 4; ++r) {
                float v = accs[f][r] + accb[wv * 64 * 17 + lane * 17 + f * 4 + r];
                const int drow = (lane >> 4) * 4 + r;       // C/D layout row
                const float lr = __shfl(ltot, drow);
                const float hp = v / lr;
                const float o  = (hp > 0.f) ? hp : (__expf(hp) - 1.f);  // elu
                out[((size_t)(b * 4096 + rbase + drow)) * 64 + f * 16 + (lane & 15)] = o;
            }
        }
    }
}

// ---------------------------------------------------------------------------
extern "C" void kernel_launch(void* const* d_in, const int* in_sizes, int n_in,
                              void* d_out, int out_size, void* d_ws, size_t ws_size,
                              hipStream_t stream) {
    const float* inp = (const float*)d_in[0];   // (8,4096,128) fp32
    const int*   adj = (const int*)d_in[1];     // (8,4096,4096) int32
    const float* W   = (const float*)d_in[2];   // (128,64) fp32
    const float* a   = (const float*)d_in[3];   // (128,1) fp32
    float* out = (float*)d_out;                 // (8,4096,64) fp32

    unsigned short* hT = (unsigned short*)d_ws;                                // 4 MiB (tiled)
    float2*  e1   = (float2*)((char*)d_ws + (size_t)4 * 1024 * 1024);          // 256 KB
    __half2* e2h  = (__half2*)((char*)d_ws + (size_t)4 * 1024 * 1024 + 262144);// 128 KB
    unsigned* mask = (unsigned*)((char*)d_ws + (size_t)6 * 1024 * 1024);       // 16 MiB

    k_pack<<<16384, 256, 0, stream>>>(adj, mask);
    k_h<<<512, 256, 0, stream>>>(inp, W, a, hT, e1, e2h);
    k_attn<<<1024, 256, 0, stream>>>(mask, hT, e1, e2h, out);
}

// Round 10
// 791.907 us; speedup vs baseline: 1.1596x; 1.1596x over previous
//
#include <hip/hip_runtime.h>
#include <hip/hip_bf16.h>
#include <hip/hip_fp16.h>
#include <cstdint>

typedef __attribute__((ext_vector_type(8))) short short8;   // 8 bf16 = 4 VGPRs
typedef __attribute__((ext_vector_type(4))) float floatx4;  // 4 fp32 acc
typedef __attribute__((ext_vector_type(4))) int   intx4;    // for nontemporal ld

#define LEAKY_ALPHA 0.2f

__device__ __forceinline__ unsigned short f2bf_rne(float f) {
    unsigned u = __float_as_uint(f);
    unsigned r = u + 0x7FFFu + ((u >> 16) & 1u);   // round-to-nearest-even
    return (unsigned short)(r >> 16);
}

__device__ __forceinline__ unsigned pk2bf(float lo, float hi) {   // v_cvt_pk_bf16_f32
    union { __hip_bfloat162 b; unsigned u; } c;
    c.b = __float22bfloat162_rn(make_float2(lo, hi));
    return c.u;
}

__device__ __forceinline__ float2 h2f2(unsigned w) {
    union { unsigned u; __half2 h; } c; c.u = w;
    return __half22float2(c.h);
}

// Within-tile column permutation (shared by k_h hT order, e2s staging, ballot
// mask): storage slot nc' = 8w + j  <->  in-tile column 4j + w  (w=0..3,j=0..7)

// ---------------------------------------------------------------------------
// Kernel 1: h = inp @ W (fp32); e1=(exp(s1),exp(.2*s1)) fp32 per row,
// e2h=(exp(s2),exp(.2*s2)) half2 per col; hT bf16 TILED+PERMUTED:
// [b][tile=n/32][o(64)][nc'] with nc' = 8*(col%4) + col/4 within the tile.
// ---------------------------------------------------------------------------
__global__ __launch_bounds__(256) void k_h(const float* __restrict__ inp,
                                           const float* __restrict__ W,
                                           const float* __restrict__ a,
                                           unsigned short* __restrict__ hT,
                                           float2* __restrict__ e1,
                                           __half2* __restrict__ e2h) {
    __shared__ float hs[64][65];   // +1 pad
    const int tid  = threadIdx.x;
    const int wv   = tid >> 6;
    const int lane = tid & 63;
    const int blk  = blockIdx.x;
    const int b     = blk >> 6;         // 0..7
    const int ibase = (blk & 63) * 64;  // row tile base

    const float a1 = a[lane];
    const float a2 = a[64 + lane];

    for (int rr = 0; rr < 16; ++rr) {
        const int rloc = wv * 16 + rr;
        const int row  = ibase + rloc;
        const float* ip = inp + ((size_t)(b * 4096 + row)) * 128;  // wave-uniform
        float acc = 0.f;
        #pragma unroll
        for (int f = 0; f < 128; f += 4) {
            float4 v = *(const float4*)(ip + f);   // uniform -> s_load
            acc += v.x * W[(f + 0) * 64 + lane];
            acc += v.y * W[(f + 1) * 64 + lane];
            acc += v.z * W[(f + 2) * 64 + lane];
            acc += v.w * W[(f + 3) * 64 + lane];
        }
        hs[rloc][lane] = acc;
        float r1 = acc * a1;
        float r2 = acc * a2;
        #pragma unroll
        for (int off = 32; off > 0; off >>= 1) {
            r1 += __shfl_xor(r1, off);
            r2 += __shfl_xor(r2, off);
        }
        if (lane == 0) {
            e1[b * 4096 + row]  = make_float2(__expf(r1), __expf(LEAKY_ALPHA * r1));
            e2h[b * 4096 + row] = __floats2half2_rn(__expf(r2), __expf(LEAKY_ALPHA * r2));
        }
    }
    __syncthreads();

    // write tiled+permuted hT: thread (o, half) writes 16 consecutive nc'
    const int o    = tid & 63;
    const int half = tid >> 6;          // 0..3
    const int tl   = half >> 1;         // local tile 0..1
    const int nco  = (half & 1) * 16;   // nc' offset 0 or 16
    unsigned pk[8];
    #pragma unroll
    for (int s = 0; s < 16; s += 2) {
        const int n0 = nco + s, n1 = nco + s + 1;
        const int c0 = 4 * (n0 & 7) + (n0 >> 3);    // permuted source col
        const int c1 = 4 * (n1 & 7) + (n1 >> 3);
        unsigned lo = f2bf_rne(hs[tl * 32 + c0][o]);   // row uniform/wave: bcast
        unsigned hi = f2bf_rne(hs[tl * 32 + c1][o]);
        pk[s >> 1] = lo | (hi << 16);
    }
    const int tile = (ibase >> 5) + tl;
    unsigned short* dst = hT + (((size_t)b * 128 + tile) * 64 + o) * 32 + nco;
    *(int4*)(dst)     = *(int4*)&pk[0];
    *(int4*)(dst + 8) = *(int4*)&pk[4];
}

// ---------------------------------------------------------------------------
// Kernel 2 (FUSED, single-barrier):
// Phase A: LANE-CONTIGUOUS adj pack — wave sweeps each 16 KB row in 16
//   NT int4 loads (1 KB contiguous per instr = 8 cache lines, vs 64 for the
//   old 128 B/lane pattern) + 4 ballots/instr -> mask64[32][16][4] in LDS:
//   bit l of mask64[r][g][q] = adj(row r, col 256g + 4l + q) > 0.
// ONE __syncthreads.
// Phase B: factorized masked softmax + PV MFMA (permuted e2su/hT consistent
//   with ballot bit order; mask via one broadcast ds_read_b64 per 8 steps;
//   depth-2 hT ring; no barriers in the hot loop).
// grid 1024 (8 b x 128 row-tiles of 32), block 256 = 4 waves, 4 blocks/CU.
// ---------------------------------------------------------------------------
__global__ __launch_bounds__(256, 4) void k_fused(const int* __restrict__ adj,
                                                  const unsigned short* __restrict__ hT,
                                                  const float2* __restrict__ e1g,
                                                  const __half2* __restrict__ e2hg,
                                                  float* __restrict__ out) {
    __shared__ unsigned long long mask64[32][16][4];   // 16 KB
    __shared__ unsigned e2su[4096];                    // permuted (E2p,E2n) half2, 16 KB

    const int tid   = threadIdx.x;
    const int b     = blockIdx.x >> 7;
    const int rtile = blockIdx.x & 127;
    const int wv    = tid >> 6;
    const int lane  = tid & 63;

    {   // stage e2h for this batch into PERMUTED slots
        const unsigned* src = (const unsigned*)(e2hg + b * 4096);
        #pragma unroll
        for (int t = 0; t < 4; ++t) {
            const int c0 = tid * 16 + t * 4;          // 4 consecutive cols, c0%4==0
            const int4 raw = *(const int4*)(src + c0);
            const int base = (c0 & ~31) + ((c0 & 31) >> 2);   // tile*32 + j
            e2su[base +  0] = (unsigned)raw.x;   // w=0
            e2su[base +  8] = (unsigned)raw.y;   // w=1
            e2su[base + 16] = (unsigned)raw.z;   // w=2
            e2su[base + 24] = (unsigned)raw.w;   // w=3
        }
    }

    // ---- Phase A: ballot pack, wave wv owns rows wv*8 .. wv*8+7 ----
    {
        const int* abase = adj + ((size_t)(b * 4096 + rtile * 32)) * 4096;
        for (int r = 0; r < 8; ++r) {
            const int lr = wv * 8 + r;
            const int* prow = abase + (size_t)lr * 4096 + lane * 4;
            #pragma unroll 4
            for (int g = 0; g < 16; ++g) {
                const intx4 v = __builtin_nontemporal_load((const intx4*)(prow + g * 256));
                const unsigned long long b0 = __ballot(v.x > 0);
                const unsigned long long b1 = __ballot(v.y > 0);
                const unsigned long long b2 = __ballot(v.z > 0);
                const unsigned long long b3 = __ballot(v.w > 0);
                if (lane == 0) {
                    ulonglong2* d = (ulonglong2*)&mask64[lr][g][0];
                    ulonglong2 t0; t0.x = b0; t0.y = b1;
                    ulonglong2 t1; t1.x = b2; t1.y = b3;
                    d[0] = t0; d[1] = t1;
                }
            }
        }
    }

    // ---- Phase B setup ----
    const int jhalf = wv >> 1;
    const int m     = lane & 15;
    const int kh    = lane >> 4;          // 0..3  (= ballot word index q = w)
    const int rl    = (wv & 1) * 16 + m;  // local row 0..31
    const int rbase = rtile * 32 + (wv & 1) * 16;
    const int row   = rbase + m;

    const float2 E1 = e1g[b * 4096 + row];
    const float E1p = E1.x, E1n = E1.y;
    const int jb0 = jhalf * 2048 + kh * 8;   // permuted e2su base

    const unsigned short* hbase =
        hT + (((size_t)b * 128 + jhalf * 64) * 64 + m) * 32 + kh * 8;
    const unsigned short* hrow0 = hbase;
    const unsigned short* hrow1 = hbase + 512;    // +16 o
    const unsigned short* hrow2 = hbase + 1024;   // +32 o
    const unsigned short* hrow3 = hbase + 1536;   // +48 o

    floatx4 acc0 = (floatx4){0.f,0.f,0.f,0.f};
    floatx4 acc1 = (floatx4){0.f,0.f,0.f,0.f};
    floatx4 acc2 = (floatx4){0.f,0.f,0.f,0.f};
    floatx4 acc3 = (floatx4){0.f,0.f,0.f,0.f};
    float lsum = 0.f;

    // depth-2 hT ring (named scalars; slot is a macro token)
    short8 rb0_0, rb1_0, rb2_0, rb3_0, rb0_1, rb1_1, rb2_1, rb3_1;
    rb0_0 = *(const short8*)(hrow0);         rb1_0 = *(const short8*)(hrow1);
    rb2_0 = *(const short8*)(hrow2);         rb3_0 = *(const short8*)(hrow3);
    rb0_1 = *(const short8*)(hrow0 + 2048);  rb1_1 = *(const short8*)(hrow1 + 2048);
    rb2_1 = *(const short8*)(hrow2 + 2048);  rb3_1 = *(const short8*)(hrow3 + 2048);

    __syncthreads();   // e2su staged + all mask64 packed (the ONLY barrier)

#define GAT_COL(WRD, T)                                                        \
    {                                                                          \
        const float2 ef = h2f2((unsigned)(WRD));                               \
        const float P  = E1p * ef.x;                                           \
        const float Nn = E1n * ef.y;                                           \
        float p = (P > 1.0f) ? P : Nn;                                         \
        p = ((mb >> (T)) & 1u) ? p : 0.0f;                                     \
        psum += p;                                                             \
        pv[T] = p;                                                             \
    }

#define GAT_STEP(SL, STEPIDX)                                                  \
    do {                                                                       \
        const short8 cb0 = rb0_##SL, cb1 = rb1_##SL;                           \
        const short8 cb2 = rb2_##SL, cb3 = rb3_##SL;                           \
        const int pstep = ((STEPIDX) + 2) & 63;        /* wrap: no OOB tail */ \
        const int poff = pstep * 2048;                 /* 4 KB tiles */        \
        rb0_##SL = *(const short8*)(hrow0 + poff);                             \
        rb1_##SL = *(const short8*)(hrow1 + poff);                             \
        rb2_##SL = *(const short8*)(hrow2 + poff);                             \
        rb3_##SL = *(const short8*)(hrow3 + poff);                             \
        const int soff = jb0 + (STEPIDX) * 32;                                 \
        const int4 eA = *(const int4*)&e2su[soff];                             \
        const int4 eB = *(const int4*)&e2su[soff + 4];                         \
        const unsigned mb = (unsigned)(Mcur >> (8 * ((STEPIDX) & 7))) & 0xffu; \
        float pv[8];                                                           \
        float psum = 0.f;                                                      \
        GAT_COL(eA.x, 0) GAT_COL(eA.y, 1) GAT_COL(eA.z, 2) GAT_COL(eA.w, 3)    \
        GAT_COL(eB.x, 4) GAT_COL(eB.y, 5) GAT_COL(eB.z, 6) GAT_COL(eB.w, 7)    \
        lsum += psum;                                                          \
        int4 ai;                                                               \
        ai.x = pk2bf(pv[0], pv[1]); ai.y = pk2bf(pv[2], pv[3]);                \
        ai.z = pk2bf(pv[4], pv[5]); ai.w = pk2bf(pv[6], pv[7]);                \
        union { int4 i; short8 s; } cc; cc.i = ai;                             \
        const short8 af = cc.s;                                                \
        acc0 = __builtin_amdgcn_mfma_f32_16x16x32_bf16(af, cb0, acc0, 0,0,0);  \
        acc1 = __builtin_amdgcn_mfma_f32_16x16x32_bf16(af, cb1, acc1, 0,0,0);  \
        acc2 = __builtin_amdgcn_mfma_f32_16x16x32_bf16(af, cb2, acc2, 0,0,0);  \
        acc3 = __builtin_amdgcn_mfma_f32_16x16x32_bf16(af, cb3, acc3, 0,0,0);  \
    } while (0)

    // ---- hot loop: 8 groups x 8 steps; mask read once per group ----
    #pragma unroll 1
    for (int p = 0; p < 8; ++p) {
        const unsigned long long Mcur =
            *(const unsigned long long*)&mask64[rl][jhalf * 8 + p][kh];
        #pragma unroll
        for (int q = 0; q < 4; ++q) {
            GAT_STEP(0, p * 8 + 2 * q);
            GAT_STEP(1, p * 8 + 2 * q + 1);
        }
    }
#undef GAT_STEP
#undef GAT_COL

    // reduce rowsum across the 4 kh-groups
    lsum += __shfl_xor(lsum, 16);
    lsum += __shfl_xor(lsum, 32);

    floatx4 accs[4] = {acc0, acc1, acc2, acc3};

    // epilogue scratch aliases the (now dead) mask LDS: [2][64][17] + [2][64]
    float* accb = (float*)&mask64[0][0][0];
    float* lb   = accb + 2 * 64 * 17;

    __syncthreads();   // mask no longer needed by any wave
    if (wv >= 2) {
        #pragma unroll
        for (int f = 0; f < 4; ++f)
            #pragma unroll
            for (int r = 0; r < 4; ++r)
                accb[(wv - 2) * 64 * 17 + lane * 17 + f * 4 + r] = accs[f][r];
        lb[(wv - 2) * 64 + lane] = lsum;
    }
    __syncthreads();
    if (wv < 2) {
        const float ltot = lsum + lb[wv * 64 + lane];
        #pragma unroll
        for (int f = 0; f < 4; ++f) {
            #pragma unroll
            for (int r = 0; r < 4; ++r) {
                float v = accs[f][r] + accb[wv * 64 * 17 + lane * 17 + f * 4 + r];
                const int drow = (lane >> 4) * 4 + r;       // C/D layout row
                const float lr = __shfl(ltot, drow);
                const float hp = v / lr;
                const float o  = (hp > 0.f) ? hp : (__expf(hp) - 1.f);  // elu
                out[((size_t)(b * 4096 + rbase + drow)) * 64 + f * 16 + (lane & 15)] = o;
            }
        }
    }
}

// ---------------------------------------------------------------------------
extern "C" void kernel_launch(void* const* d_in, const int* in_sizes, int n_in,
                              void* d_out, int out_size, void* d_ws, size_t ws_size,
                              hipStream_t stream) {
    const float* inp = (const float*)d_in[0];   // (8,4096,128) fp32
    const int*   adj = (const int*)d_in[1];     // (8,4096,4096) int32
    const float* W   = (const float*)d_in[2];   // (128,64) fp32
    const float* a   = (const float*)d_in[3];   // (128,1) fp32
    float* out = (float*)d_out;                 // (8,4096,64) fp32

    unsigned short* hT = (unsigned short*)d_ws;                                // 4 MiB (tiled+perm)
    float2*  e1  = (float2*)((char*)d_ws + (size_t)4 * 1024 * 1024);           // 256 KB
    __half2* e2h = (__half2*)((char*)d_ws + (size_t)4 * 1024 * 1024 + 262144); // 128 KB

    k_h<<<512, 256, 0, stream>>>(inp, W, a, hT, e1, e2h);
    k_fused<<<1024, 256, 0, stream>>>(adj, hT, e1, e2h, out);
}